// Round 5
// baseline (153.727 us; speedup 1.0000x reference)
//
#include <hip/hip_runtime.h>

#define B_ 16
#define C_ 128
#define N_ 1024
#define K_ 9
#define NEG_SLOPE 0.2f
#define BN_EPS 1e-5f

typedef __attribute__((ext_vector_type(8))) short short8;
typedef __attribute__((ext_vector_type(4))) float f32x4;
typedef __attribute__((ext_vector_type(4))) unsigned short u16x4;

__device__ __forceinline__ unsigned short f2bf(float f) {
    union { float f; unsigned u; } v; v.f = f;
    unsigned r = v.u + 0x7fffu + ((v.u >> 16) & 1u);   // RNE
    return (unsigned short)(r >> 16);
}
__device__ __forceinline__ float bf2f(unsigned short h) {
    union { unsigned u; float f; } v; v.u = ((unsigned)h) << 16; return v.f;
}
__device__ __forceinline__ unsigned umin_(unsigned a, unsigned b) { return a < b ? a : b; }

// ---- k_stage (R18): fused transpose + prep + prepack.
__global__ __launch_bounds__(256) void k_stage(const float* __restrict__ x,
        const float* __restrict__ W1, const float* __restrict__ W2,
        float* __restrict__ featsT, unsigned short* __restrict__ Bf,
        float* __restrict__ sq, unsigned short* __restrict__ wf1,
        unsigned short* __restrict__ wf2)
{
    int blk = blockIdx.x;
    int tid = threadIdx.x;

    if (blk >= 512) {                             // ---- prepack region
        int t = (blk - 512) * 256 + tid;          // 6144 threads
        if (t < 4096) {                           // W1: kk 0..7
            int kk = t >> 9, w = (t >> 6) & 7, lane = t & 63;
            int quad = lane >> 4, col = lane & 15;
            #pragma unroll
            for (int j = 0; j < 8; ++j)
                wf1[t * 8 + j] = f2bf(W1[(kk * 32 + quad * 8 + j) * C_ + 16 * w + col]);
        } else {                                  // W2: kk 0..3
            int t2 = t - 4096;
            int kk = t2 >> 9, w = (t2 >> 6) & 7, lane = t2 & 63;
            int quad = lane >> 4, col = lane & 15;
            #pragma unroll
            for (int j = 0; j < 8; ++j)
                wf2[t2 * 8 + j] = f2bf(W2[(kk * 32 + quad * 8 + j) * C_ + 16 * w + col]);
        }
        return;
    }

    __shared__ float tch[128][33];                // 16.9 KB, +1 pad
    int b = blk >> 5;                             // 16 b x 32 ntiles
    int n0 = (blk & 31) * 32;

    // ---- load x tile (float4-coalesced)
    const float4* xv = (const float4*)x;
    #pragma unroll
    for (int pass = 0; pass < 4; ++pass) {
        int c = pass * 32 + (tid >> 3);
        int f = tid & 7;
        float4 v = xv[(b * C_ + c) * 256 + (n0 >> 2) + f];
        tch[c][f * 4 + 0] = v.x; tch[c][f * 4 + 1] = v.y;
        tch[c][f * 4 + 2] = v.z; tch[c][f * 4 + 3] = v.w;
    }
    __syncthreads();

    // ---- featsT write (coalesced: 128 consecutive ch per point)
    #pragma unroll
    for (int pass = 0; pass < 16; ++pass) {
        int li = pass * 256 + tid;
        int p = li >> 7, c = li & 127;
        featsT[(b * N_ + n0 + p) * C_ + c] = tch[c][p];
    }

    // ---- Bf + sq (source = LDS); 8 points per sub-iter
    int lane = tid & 63, wv = tid >> 6;
    int half = lane >> 5, l2 = lane & 31;
    int ch0 = (l2 & 15) * 8;
    #pragma unroll
    for (int sub = 0; sub < 4; ++sub) {
        int pl = sub * 8 + wv * 2 + half;
        int n = n0 + pl;
        float a0 = tch[ch0 + 0][pl], a1 = tch[ch0 + 1][pl];
        float a2 = tch[ch0 + 2][pl], a3 = tch[ch0 + 3][pl];
        float a4 = tch[ch0 + 4][pl], a5 = tch[ch0 + 5][pl];
        float a6 = tch[ch0 + 6][pl], a7 = tch[ch0 + 7][pl];

        u16x4 o0, o1;
        if (l2 < 16) {
            o0.x = f2bf(a0); o0.y = f2bf(a1); o0.z = f2bf(a2); o0.w = f2bf(a3);
            o1.x = f2bf(a4); o1.y = f2bf(a5); o1.z = f2bf(a6); o1.w = f2bf(a7);
        } else {
            o0.x = f2bf(a0 - bf2f(f2bf(a0))); o0.y = f2bf(a1 - bf2f(f2bf(a1)));
            o0.z = f2bf(a2 - bf2f(f2bf(a2))); o0.w = f2bf(a3 - bf2f(f2bf(a3)));
            o1.x = f2bf(a4 - bf2f(f2bf(a4))); o1.y = f2bf(a5 - bf2f(f2bf(a5)));
            o1.z = f2bf(a6 - bf2f(f2bf(a6))); o1.w = f2bf(a7 - bf2f(f2bf(a7)));
        }
        long chunk = (((long)(b * 8 + (l2 >> 2)) * 64 + (n >> 4)) << 6)
                   + ((l2 & 3) * 16 + (n & 15));
        *(u16x4*)&Bf[chunk * 8]     = o0;
        *(u16x4*)&Bf[chunk * 8 + 4] = o1;

        float ss = a0*a0 + a1*a1 + a2*a2 + a3*a3 + a4*a4 + a5*a5 + a6*a6 + a7*a7;
        #pragma unroll
        for (int off = 1; off < 16; off <<= 1)
            ss += __shfl_xor(ss, off);
        if (l2 == 0) sq[b * N_ + n] = ss;
    }
}

// --------------- MFMA KNN v4 (R19): 16 rows x 1024 cols per block, but the
// selection geometry flipped: 32 lanes per row, 2 rows per wave, 32 cand/lane.
// ONE 5-step shfl_xor chain (offs 1..16 stay within the 32-lane half) now
// serves BOTH rows per round -- 5 shuffles/round vs 12, one ballot vs two.
// Keys, lex tie-break, and rebuild are bit-identical to the R16-verified
// logic. keybuf stride 1032 words: both write (quad-parity) and read
// (kr*8+l32) patterns land exactly 2 lanes/bank = conflict-free.
__global__ __launch_bounds__(512, 4) void k_knn(
        const unsigned short* __restrict__ Bf, const float* __restrict__ sq,
        int* __restrict__ idxout)
{
    __shared__ unsigned keybuf[8][1032];
    __shared__ float sqn[16];

    int L = blockIdx.x;                       // 1024 = 16 b * 64 tiles
    int xcd = L & 7, slot = L >> 3;
    int b = xcd * 2 + (slot >> 6);
    int tile = slot & 63;
    int n0 = tile * 16;
    int tid = threadIdx.x;

    if (tid < 16) sqn[tid] = sq[b * N_ + n0 + tid];
    __syncthreads();

    int wv = tid >> 6, lane = tid & 63, quad = lane >> 4, cl = lane & 15;

    f32x4 acc[8];
    #pragma unroll
    for (int t = 0; t < 8; ++t) acc[t] = (f32x4){0.f, 0.f, 0.f, 0.f};

    const short8* bfp = (const short8*)Bf;
    #pragma unroll
    for (int kb = 0; kb < 4; ++kb) {
        long abase = (((long)(b * 8 + kb) * 64 + tile) << 6) + quad * 16 + cl;
        short8 afh = bfp[abase];
        short8 afl = bfp[abase + 16384];      // +4*64*64 chunks (lo table)
        long bh = (((long)(b * 8 + kb) * 64 + wv * 8) << 6) + lane;
        long bl = bh + 16384;
        #pragma unroll
        for (int t = 0; t < 8; ++t) {         // B-hi: hiA*hiB + loA*hiB
            short8 bfr = bfp[bh + t * 64];
            acc[t] = __builtin_amdgcn_mfma_f32_16x16x32_bf16(afh, bfr, acc[t], 0, 0, 0);
            acc[t] = __builtin_amdgcn_mfma_f32_16x16x32_bf16(afl, bfr, acc[t], 0, 0, 0);
        }
        #pragma unroll
        for (int t = 0; t < 8; ++t) {         // B-lo: hiA*loB
            short8 bfr = bfp[bl + t * 64];
            acc[t] = __builtin_amdgcn_mfma_f32_16x16x32_bf16(afh, bfr, acc[t], 0, 0, 0);
        }
    }

    // convert acc -> monotone u32 keys (EXACT)
    float smc[8];
    #pragma unroll
    for (int t = 0; t < 8; ++t)
        smc[t] = sq[b * N_ + ((wv * 8 + t) << 4) + cl];

    unsigned karr[8][4];
    #pragma unroll
    for (int t = 0; t < 8; ++t)
        #pragma unroll
        for (int r = 0; r < 4; ++r) {
            float d2 = fmaf(-2.f, acc[t][r], smc[t] + sqn[quad * 4 + r]);
            unsigned bits = __float_as_uint(d2);
            karr[t][r] = bits ^ ((unsigned)((int)bits >> 31) | 0x80000000u);
        }

    // 2-phase staging: phase ph stages rows quad*4 + {2ph, 2ph+1} into
    // keybuf[quad*2 + {0,1}]; waves 0-3 read at ph0, waves 4-7 at ph1.
    int grp = lane >> 5, l32 = lane & 31;
    int myphase = wv >> 2;
    int kr_r = ((wv & 3) << 1) + grp;         // reader's keybuf row 0..7
    unsigned v[32];
    #pragma unroll
    for (int ph = 0; ph < 2; ++ph) {
        #pragma unroll
        for (int t = 0; t < 8; ++t) {
            int col = ((wv * 8 + t) << 4) + cl;
            keybuf[quad * 2 + 0][col] = karr[t][ph * 2 + 0];
            keybuf[quad * 2 + 1][col] = karr[t][ph * 2 + 1];
        }
        __syncthreads();
        if (myphase == ph) {
            #pragma unroll
            for (int j = 0; j < 32; ++j)
                v[j] = keybuf[kr_r][(j << 5) + l32];   // col = j*32 + l32
        }
        __syncthreads();
    }

    // this wave's output row: keybuf row kr decodes to quad*4 + 2*ph + r
    int rowq = ((kr_r >> 1) << 2) + (myphase << 1) + (kr_r & 1);
    long orow = (long)(b * N_ + n0 + rowq) * K_;

    // per-lane online top-2 of (key, j), strict '<' keeps ascending j on ties
    unsigned m1 = 0xFFFFFFFFu, m2 = 0xFFFFFFFFu, j1 = 0, j2 = 0;
    #pragma unroll
    for (int j = 0; j < 32; ++j) {
        unsigned x_ = v[j], jc = (unsigned)j;
        bool b1 = x_ < m1, b2 = x_ < m2;
        unsigned tk = b1 ? m1 : x_, tj = b1 ? j1 : jc;
        m2 = b2 ? tk : m2; j2 = b2 ? tj : j2;
        m1 = b1 ? x_ : m1; j1 = b1 ? jc : j1;
    }

    #pragma unroll 1
    for (int q = 0; q < K_; ++q) {
        unsigned g = m1;
        #pragma unroll
        for (int off = 1; off < 32; off <<= 1)     // 5 steps, stays in 32-half
            g = umin_(g, (unsigned)__shfl_xor((int)g, off));

        bool tied = (m1 == g);
        unsigned long long bal = __ballot(tied);
        unsigned balg = (unsigned)(bal >> (grp << 5));  // this group's 32 bits
        bool win;
        if (__popc(balg) > 1) {        // group-uniform; rare exact key ties
            unsigned mc = tied ? ((j1 << 5) + (unsigned)l32) : 0xFFFFFFFFu;
            unsigned cm = mc;
            #pragma unroll
            for (int off = 1; off < 32; off <<= 1)
                cm = umin_(cm, (unsigned)__shfl_xor((int)cm, off));
            win = tied && (mc == cm);  // smallest column wins
        } else {
            win = tied;
        }
        if (win) {
            idxout[orow + q] = (int)((j1 << 5) + (unsigned)l32);
            unsigned gk = m1, gj = j1;
            m1 = m2; j1 = j2; m2 = 0xFFFFFFFFu;
            if (m1 == 0xFFFFFFFFu) {   // exhausted: exact lex rebuild
                #pragma unroll
                for (int j = 0; j < 32; ++j) {
                    unsigned x_ = v[j], jc = (unsigned)j;
                    bool dead = (x_ < gk) || (x_ == gk && jc <= gj);
                    unsigned xk = dead ? 0xFFFFFFFFu : x_;
                    bool b1 = xk < m1, b2 = xk < m2;
                    unsigned tk = b1 ? m1 : xk, tj = b1 ? j1 : jc;
                    m2 = b2 ? tk : m2; j2 = b2 ? tj : j2;
                    m1 = b1 ? xk : m1; j1 = b1 ? jc : j1;
                }
            }
        }
    }
}

// ------- MFMA edge-MLP + maxpool: block = 8 points (72 edges, padded to 80 rows)
__global__ __launch_bounds__(512, 6) void k_edge(const float* __restrict__ featsT,
        const int* __restrict__ idx, const unsigned short* __restrict__ wf1,
        const unsigned short* __restrict__ wf2, const float* __restrict__ b1,
        const float* __restrict__ b2, float* __restrict__ msg)
{
    __shared__ __align__(16) char smem[52224];
    unsigned short* diffs = (unsigned short*)smem;
    unsigned short* cenb  = (unsigned short*)(smem + 21760);
    unsigned short* h2b   = (unsigned short*)smem;
    unsigned short* h1    = (unsigned short*)(smem + 26112);
    unsigned short* ccb   = (unsigned short*)(smem + 47872);
    __shared__ int nb[72];

    int L = blockIdx.x;                 // 2048 = 8 xcd * 256 slots
    int xcd = L & 7, slot = L >> 3;
    int b = xcd * 2 + (slot >> 7);
    int tile = slot & 127;
    int n0 = tile * 8;
    int tid = threadIdx.x;

    if (tid < 72) nb[tid] = idx[(b * N_ + n0 + tid / 9) * K_ + tid % 9];
    __syncthreads();

    // ---- gather: 64 threads per point; halves split the 9 edges 5/4
    {
        int g = tid >> 6, j = tid & 63;
        int chunk = j & 31, ch = chunk << 2, half = j >> 5;
        const float4* fT4 = (const float4*)featsT;
        float4 cv = fT4[(b * N_ + n0 + g) * 32 + chunk];
        if (half == 0) {
            u16x4 cb; cb.x = f2bf(cv.x); cb.y = f2bf(cv.y);
            cb.z = f2bf(cv.z); cb.w = f2bf(cv.w);
            *(u16x4*)&cenb[g * 136 + ch] = cb;
        }
        int qb = half ? 5 : 0, qe = half ? 9 : 5;
        for (int q = qb; q < qe; ++q) {
            int e = g * 9 + q;
            float4 nv = fT4[(b * N_ + nb[e]) * 32 + chunk];
            u16x4 db;
            db.x = f2bf(nv.x - cv.x); db.y = f2bf(nv.y - cv.y);
            db.z = f2bf(nv.z - cv.z); db.w = f2bf(nv.w - cv.w);
            *(u16x4*)&diffs[e * 136 + ch] = db;
        }
    }
    __syncthreads();

    int wv = tid >> 6, lane = tid & 63;
    int quad = lane >> 4, cl = lane & 15;
    const short8* w1f = (const short8*)wf1;
    const short8* w2f = (const short8*)wf2;

    // ---- G1a: centers @ W1_top + b1 -> cc
    {
        float b1v = b1[16 * wv + cl];
        f32x4 a = (f32x4){b1v, b1v, b1v, b1v};
        #pragma unroll
        for (int kk = 0; kk < 4; ++kk) {
            short8 af = *(const short8*)&cenb[cl * 136 + kk * 32 + quad * 8];
            short8 bf = w1f[(kk * 8 + wv) * 64 + lane];
            a = __builtin_amdgcn_mfma_f32_16x16x32_bf16(af, bf, a, 0, 0, 0);
        }
        #pragma unroll
        for (int r = 0; r < 4; ++r)
            ccb[(quad * 4 + r) * 136 + 16 * wv + cl] = f2bf(a[r]);
    }

    // ---- G1b: diffs @ W1_bot, + cc[point], leaky -> h1 (weights hoisted)
    {
        short8 wb[4];
        #pragma unroll
        for (int kb = 0; kb < 4; ++kb)
            wb[kb] = w1f[((kb + 4) * 8 + wv) * 64 + lane];
        #pragma unroll
        for (int t = 0; t < 5; ++t) {
            f32x4 a = (f32x4){0.f, 0.f, 0.f, 0.f};
            #pragma unroll
            for (int kb = 0; kb < 4; ++kb) {
                short8 af = *(const short8*)&diffs[(16 * t + cl) * 136 + kb * 32 + quad * 8];
                a = __builtin_amdgcn_mfma_f32_16x16x32_bf16(af, wb[kb], a, 0, 0, 0);
            }
            #pragma unroll
            for (int r = 0; r < 4; ++r) {
                int row = 16 * t + quad * 4 + r;
                int pt = row / 9; if (pt > 7) pt = 7;
                float v = a[r] + bf2f(ccb[pt * 136 + 16 * wv + cl]);
                v = (v >= 0.f) ? v : NEG_SLOPE * v;
                h1[row * 136 + 16 * wv + cl] = f2bf(v);
            }
        }
    }
    __syncthreads();

    // ---- GEMM2: h1 @ W2 -> h2 (bf16, aliases dead diffs; weights hoisted)
    {
        short8 wb[4];
        #pragma unroll
        for (int kb = 0; kb < 4; ++kb)
            wb[kb] = w2f[(kb * 8 + wv) * 64 + lane];
        #pragma unroll
        for (int t = 0; t < 5; ++t) {
            f32x4 a = (f32x4){0.f, 0.f, 0.f, 0.f};
            #pragma unroll
            for (int kb = 0; kb < 4; ++kb) {
                short8 af = *(const short8*)&h1[(16 * t + cl) * 136 + kb * 32 + quad * 8];
                a = __builtin_amdgcn_mfma_f32_16x16x32_bf16(af, wb[kb], a, 0, 0, 0);
            }
            #pragma unroll
            for (int r = 0; r < 4; ++r)
                h2b[(16 * t + quad * 4 + r) * 136 + 16 * wv + cl] = f2bf(a[r]);
        }
    }
    __syncthreads();

    // ---- maxpool over 9 edges/point + bias, write msg (B,C,N)
    int p = tid & 7, nb8 = tid >> 3;      // nb8: 0..63
    #pragma unroll
    for (int it = 0; it < 2; ++it) {
        int n = nb8 + 64 * it;
        float m = bf2f(h2b[(p * 9) * 136 + n]);
        #pragma unroll
        for (int q = 1; q < 9; ++q)
            m = fmaxf(m, bf2f(h2b[(p * 9 + q) * 136 + n]));
        msg[(b * C_ + n) * N_ + n0 + p] = m + b2[n];
    }
}

// ---------------------------------------------------- BN statistics per channel
__global__ __launch_bounds__(256) void k_bnstats(const float* __restrict__ msg,
        const float* __restrict__ gamma, const float* __restrict__ beta,
        float* __restrict__ scale, float* __restrict__ shift)
{
    int c = blockIdx.x, tid = threadIdx.x;
    const float4* m4 = (const float4*)msg;
    float4 s4 = {0.f, 0.f, 0.f, 0.f}, ss4 = {0.f, 0.f, 0.f, 0.f};
    #pragma unroll
    for (int b = 0; b < B_; ++b) {
        float4 v = m4[(b * C_ + c) * 256 + tid];
        s4.x += v.x; s4.y += v.y; s4.z += v.z; s4.w += v.w;
        ss4.x += v.x * v.x; ss4.y += v.y * v.y;
        ss4.z += v.z * v.z; ss4.w += v.w * v.w;
    }
    float s = (s4.x + s4.y) + (s4.z + s4.w);
    float ss = (ss4.x + ss4.y) + (ss4.z + ss4.w);
    __shared__ float rs[256], rss[256];
    rs[tid] = s; rss[tid] = ss;
    __syncthreads();
    for (int off = 128; off > 0; off >>= 1) {
        if (tid < off) { rs[tid] += rs[tid + off]; rss[tid] += rss[tid + off]; }
        __syncthreads();
    }
    if (tid == 0) {
        float mean = rs[0] / (float)(B_ * N_);
        float var = rss[0] / (float)(B_ * N_) - mean * mean;
        float inv = 1.0f / sqrtf(var + BN_EPS);
        float g = gamma[c];
        scale[c] = g * inv;
        shift[c] = beta[c] - g * inv * mean;
    }
}

// ------------------------------------------- BN apply + residual + final ReLU
__global__ __launch_bounds__(256) void k_final(const float* __restrict__ msg,
        const float* __restrict__ x, const float* __restrict__ scale,
        const float* __restrict__ shift, float* __restrict__ out)
{
    int i = blockIdx.x * 256 + threadIdx.x;
    int e = i << 2;
    int c = (e >> 10) & 127;
    float sc = scale[c], sh = shift[c];
    float4 m4 = reinterpret_cast<const float4*>(msg)[i];
    float4 x4 = reinterpret_cast<const float4*>(x)[i];
    float4 o;
    o.x = fmaxf(m4.x * sc + sh + x4.x, 0.f);
    o.y = fmaxf(m4.y * sc + sh + x4.y, 0.f);
    o.z = fmaxf(m4.z * sc + sh + x4.z, 0.f);
    o.w = fmaxf(m4.w * sc + sh + x4.w, 0.f);
    reinterpret_cast<float4*>(out)[i] = o;
}

extern "C" void kernel_launch(void* const* d_in, const int* in_sizes, int n_in,
                              void* d_out, int out_size, void* d_ws, size_t ws_size,
                              hipStream_t stream)
{
    const float* x     = (const float*)d_in[0];
    const float* W1    = (const float*)d_in[1];
    const float* b1    = (const float*)d_in[2];
    const float* W2    = (const float*)d_in[3];
    const float* b2    = (const float*)d_in[4];
    const float* gamma = (const float*)d_in[5];
    const float* beta  = (const float*)d_in[6];
    float* out = (float*)d_out;

    float* ws     = (float*)d_ws;
    float* featsT = ws;                     // 8 MB, live through k_edge
    float* msg    = ws + 2097152;           // 8 MB; Bf aliases (dead before k_edge)
    unsigned short* Bf = (unsigned short*)(ws + 2097152);
    float* sq     = ws + 4194304;           // 16384
    float* scale  = ws + 4210688;           // 128
    float* shift  = ws + 4210816;           // 128
    int*   idx    = (int*)(ws + 4210944);   // 147456 ints
    unsigned short* wf1 = (unsigned short*)(ws + 4358400);  // 32768 bf16
    unsigned short* wf2 = (unsigned short*)(ws + 4374784);  // 16384 bf16

    k_stage  <<< 536, 256, 0, stream>>>(x, W1, W2, featsT, Bf, sq, wf1, wf2);
    k_knn    <<<1024, 512, 0, stream>>>(Bf, sq, idx);
    k_edge   <<<2048, 512, 0, stream>>>(featsT, idx, wf1, wf2, b1, b2, msg);
    k_bnstats<<< 128, 256, 0, stream>>>(msg, gamma, beta, scale, shift);
    k_final  <<<2048, 256, 0, stream>>>(msg, x, scale, shift, out);
}

// Round 6
// 141.187 us; speedup vs baseline: 1.0888x; 1.0888x over previous
//
#include <hip/hip_runtime.h>

#define B_ 16
#define C_ 128
#define N_ 1024
#define K_ 9
#define NEG_SLOPE 0.2f
#define BN_EPS 1e-5f

typedef __attribute__((ext_vector_type(8))) short short8;
typedef __attribute__((ext_vector_type(4))) float f32x4;
typedef __attribute__((ext_vector_type(4))) unsigned short u16x4;

__device__ __forceinline__ unsigned short f2bf(float f) {
    union { float f; unsigned u; } v; v.f = f;
    unsigned r = v.u + 0x7fffu + ((v.u >> 16) & 1u);   // RNE
    return (unsigned short)(r >> 16);
}
__device__ __forceinline__ float bf2f(unsigned short h) {
    union { unsigned u; float f; } v; v.u = ((unsigned)h) << 16; return v.f;
}
__device__ __forceinline__ unsigned umin_(unsigned a, unsigned b) { return a < b ? a : b; }

// ---- k_stage (R18): fused transpose + prep + prepack.
// R20: prepack block 512 also zeroes the BN accumulator (ws is re-poisoned
// every iteration, so explicit zeroing is mandatory).
__global__ __launch_bounds__(256) void k_stage(const float* __restrict__ x,
        const float* __restrict__ W1, const float* __restrict__ W2,
        float* __restrict__ featsT, unsigned short* __restrict__ Bf,
        float* __restrict__ sq, unsigned short* __restrict__ wf1,
        unsigned short* __restrict__ wf2, float* __restrict__ bnacc)
{
    int blk = blockIdx.x;
    int tid = threadIdx.x;

    if (blk >= 512) {                             // ---- prepack region
        if (blk == 512) bnacc[tid] = 0.f;         // 256 floats: sum/ss per ch
        int t = (blk - 512) * 256 + tid;          // 6144 threads
        if (t < 4096) {                           // W1: kk 0..7
            int kk = t >> 9, w = (t >> 6) & 7, lane = t & 63;
            int quad = lane >> 4, col = lane & 15;
            #pragma unroll
            for (int j = 0; j < 8; ++j)
                wf1[t * 8 + j] = f2bf(W1[(kk * 32 + quad * 8 + j) * C_ + 16 * w + col]);
        } else {                                  // W2: kk 0..3
            int t2 = t - 4096;
            int kk = t2 >> 9, w = (t2 >> 6) & 7, lane = t2 & 63;
            int quad = lane >> 4, col = lane & 15;
            #pragma unroll
            for (int j = 0; j < 8; ++j)
                wf2[t2 * 8 + j] = f2bf(W2[(kk * 32 + quad * 8 + j) * C_ + 16 * w + col]);
        }
        return;
    }

    __shared__ float tch[128][33];                // 16.9 KB, +1 pad
    int b = blk >> 5;                             // 16 b x 32 ntiles
    int n0 = (blk & 31) * 32;

    // ---- load x tile (float4-coalesced)
    const float4* xv = (const float4*)x;
    #pragma unroll
    for (int pass = 0; pass < 4; ++pass) {
        int c = pass * 32 + (tid >> 3);
        int f = tid & 7;
        float4 v = xv[(b * C_ + c) * 256 + (n0 >> 2) + f];
        tch[c][f * 4 + 0] = v.x; tch[c][f * 4 + 1] = v.y;
        tch[c][f * 4 + 2] = v.z; tch[c][f * 4 + 3] = v.w;
    }
    __syncthreads();

    // ---- featsT write (coalesced: 128 consecutive ch per point)
    #pragma unroll
    for (int pass = 0; pass < 16; ++pass) {
        int li = pass * 256 + tid;
        int p = li >> 7, c = li & 127;
        featsT[(b * N_ + n0 + p) * C_ + c] = tch[c][p];
    }

    // ---- Bf + sq (source = LDS); 8 points per sub-iter
    int lane = tid & 63, wv = tid >> 6;
    int half = lane >> 5, l2 = lane & 31;
    int ch0 = (l2 & 15) * 8;
    #pragma unroll
    for (int sub = 0; sub < 4; ++sub) {
        int pl = sub * 8 + wv * 2 + half;
        int n = n0 + pl;
        float a0 = tch[ch0 + 0][pl], a1 = tch[ch0 + 1][pl];
        float a2 = tch[ch0 + 2][pl], a3 = tch[ch0 + 3][pl];
        float a4 = tch[ch0 + 4][pl], a5 = tch[ch0 + 5][pl];
        float a6 = tch[ch0 + 6][pl], a7 = tch[ch0 + 7][pl];

        u16x4 o0, o1;
        if (l2 < 16) {
            o0.x = f2bf(a0); o0.y = f2bf(a1); o0.z = f2bf(a2); o0.w = f2bf(a3);
            o1.x = f2bf(a4); o1.y = f2bf(a5); o1.z = f2bf(a6); o1.w = f2bf(a7);
        } else {
            o0.x = f2bf(a0 - bf2f(f2bf(a0))); o0.y = f2bf(a1 - bf2f(f2bf(a1)));
            o0.z = f2bf(a2 - bf2f(f2bf(a2))); o0.w = f2bf(a3 - bf2f(f2bf(a3)));
            o1.x = f2bf(a4 - bf2f(f2bf(a4))); o1.y = f2bf(a5 - bf2f(f2bf(a5)));
            o1.z = f2bf(a6 - bf2f(f2bf(a6))); o1.w = f2bf(a7 - bf2f(f2bf(a7)));
        }
        long chunk = (((long)(b * 8 + (l2 >> 2)) * 64 + (n >> 4)) << 6)
                   + ((l2 & 3) * 16 + (n & 15));
        *(u16x4*)&Bf[chunk * 8]     = o0;
        *(u16x4*)&Bf[chunk * 8 + 4] = o1;

        float ss = a0*a0 + a1*a1 + a2*a2 + a3*a3 + a4*a4 + a5*a5 + a6*a6 + a7*a7;
        #pragma unroll
        for (int off = 1; off < 16; off <<= 1)
            ss += __shfl_xor(ss, off);
        if (l2 == 0) sq[b * N_ + n] = ss;
    }
}

// --------------- MFMA KNN (R17, reinstated after R19 regression): 32 rows x
// 1024 cols per block; selection = 4 row-phases staged to regs, ONE 9-round
// loop with 4 INTERLEAVED 64-lane butterflies. R19 proved the selection is
// latency-bound on the shuffle chain: 4 independent chains/wave are needed
// to hide it (1 chain = VALUBusy 36%, +10us). Exact keys + lex tie/rebuild.
#define STAGE_READ(PH, VARR) do {                                              \
    const int tl_ = (PH) >> 1, rb_ = ((PH) & 1) * 2;                           \
    _Pragma("unroll")                                                          \
    for (int t = 0; t < 8; ++t) {                                              \
        int col = ((wv * 8 + t) << 4) + cl;                                    \
        keybuf[quad * 2 + 0][col] = karr[tl_][t][rb_ + 0];                     \
        keybuf[quad * 2 + 1][col] = karr[tl_][t][rb_ + 1];                     \
    }                                                                          \
    __syncthreads();                                                           \
    _Pragma("unroll")                                                          \
    for (int j = 0; j < 16; ++j) VARR[j] = keybuf[wv][lane + (j << 6)];        \
    __syncthreads();                                                           \
} while (0)

#define TOP2_INIT(VARR, M1, M2, J1, J2) do {                                   \
    M1 = 0xFFFFFFFFu; M2 = 0xFFFFFFFFu; J1 = 0; J2 = 0;                        \
    _Pragma("unroll")                                                          \
    for (int j = 0; j < 16; ++j) {                                             \
        unsigned x_ = VARR[j], jc_ = (unsigned)j;                              \
        bool b1_ = x_ < M1, b2_ = x_ < M2;                                     \
        unsigned tk_ = b1_ ? M1 : x_, tj_ = b1_ ? J1 : jc_;                    \
        M2 = b2_ ? tk_ : M2; J2 = b2_ ? tj_ : J2;                              \
        M1 = b1_ ? x_ : M1; J1 = b1_ ? jc_ : J1;                               \
    }                                                                          \
} while (0)

#define ROW_ROUND(VARR, M1, M2, J1, J2, G, ROWPTR) do {                        \
    bool t_ = (M1 == (G));                                                     \
    unsigned long long bal_ = __ballot(t_);                                    \
    bool win_;                                                                 \
    if (__popcll(bal_) > 1) {            /* wave-uniform; rare exact ties */   \
        unsigned mc_ = t_ ? (unsigned)(lane + (J1 << 6)) : 0xFFFFFFFFu;        \
        unsigned cm_ = mc_;                                                    \
        _Pragma("unroll")                                                      \
        for (int off = 1; off < 64; off <<= 1)                                 \
            cm_ = umin_(cm_, (unsigned)__shfl_xor((int)cm_, off));             \
        win_ = t_ && (mc_ == cm_);       /* smallest column wins */            \
    } else {                                                                   \
        win_ = t_;                                                             \
    }                                                                          \
    if (win_) {                                                                \
        idxout[(ROWPTR) + q] = lane + (int)(J1 << 6);                          \
        unsigned gk_ = M1, gj_ = J1;                                           \
        M1 = M2; J1 = J2; M2 = 0xFFFFFFFFu;                                    \
        if (M1 == 0xFFFFFFFFu) {         /* exhausted: exact lex rebuild */    \
            _Pragma("unroll")                                                  \
            for (int j = 0; j < 16; ++j) {                                     \
                unsigned x_ = VARR[j], jc_ = (unsigned)j;                      \
                bool dead_ = (x_ < gk_) || (x_ == gk_ && jc_ <= gj_);          \
                unsigned xk_ = dead_ ? 0xFFFFFFFFu : x_;                       \
                bool b1_ = xk_ < M1, b2_ = xk_ < M2;                           \
                unsigned tk_ = b1_ ? M1 : xk_, tj_ = b1_ ? J1 : jc_;           \
                M2 = b2_ ? tk_ : M2; J2 = b2_ ? tj_ : J2;                      \
                M1 = b1_ ? xk_ : M1; J1 = b1_ ? jc_ : J1;                      \
            }                                                                  \
        }                                                                      \
    }                                                                          \
} while (0)

__global__ __launch_bounds__(512, 4) void k_knn(
        const unsigned short* __restrict__ Bf, const float* __restrict__ sq,
        int* __restrict__ idxout)
{
    __shared__ unsigned keybuf[8][1028];
    __shared__ float sqn[32];

    int L = blockIdx.x;                       // 512 = 16 b * 32 tile32
    int xcd = L & 7, slot = L >> 3;
    int b = xcd * 2 + (slot >> 5);
    int tile32 = slot & 31;
    int n0 = tile32 * 32;
    int tid = threadIdx.x;

    if (tid < 32) sqn[tid] = sq[b * N_ + n0 + tid];
    __syncthreads();

    int wv = tid >> 6, lane = tid & 63, quad = lane >> 4, cl = lane & 15;

    f32x4 acc[2][8];
    #pragma unroll
    for (int tl = 0; tl < 2; ++tl)
        #pragma unroll
        for (int t = 0; t < 8; ++t) acc[tl][t] = (f32x4){0.f, 0.f, 0.f, 0.f};

    const short8* bfp = (const short8*)Bf;
    #pragma unroll
    for (int kb = 0; kb < 4; ++kb) {
        long ab0 = (((long)(b * 8 + kb) * 64 + tile32 * 2) << 6) + quad * 16 + cl;
        short8 afh0 = bfp[ab0];
        short8 afl0 = bfp[ab0 + 16384];       // +4*64*64 chunks (lo table)
        short8 afh1 = bfp[ab0 + 64];
        short8 afl1 = bfp[ab0 + 16384 + 64];
        long bh = (((long)(b * 8 + kb) * 64 + wv * 8) << 6) + lane;
        long bl = bh + 16384;
        #pragma unroll
        for (int t = 0; t < 8; ++t) {         // B-hi: hiA*hiB + loA*hiB, both tiles
            short8 bfr = bfp[bh + t * 64];
            acc[0][t] = __builtin_amdgcn_mfma_f32_16x16x32_bf16(afh0, bfr, acc[0][t], 0, 0, 0);
            acc[0][t] = __builtin_amdgcn_mfma_f32_16x16x32_bf16(afl0, bfr, acc[0][t], 0, 0, 0);
            acc[1][t] = __builtin_amdgcn_mfma_f32_16x16x32_bf16(afh1, bfr, acc[1][t], 0, 0, 0);
            acc[1][t] = __builtin_amdgcn_mfma_f32_16x16x32_bf16(afl1, bfr, acc[1][t], 0, 0, 0);
        }
        #pragma unroll
        for (int t = 0; t < 8; ++t) {         // B-lo: hiA*loB, both tiles
            short8 bfr = bfp[bl + t * 64];
            acc[0][t] = __builtin_amdgcn_mfma_f32_16x16x32_bf16(afh0, bfr, acc[0][t], 0, 0, 0);
            acc[1][t] = __builtin_amdgcn_mfma_f32_16x16x32_bf16(afh1, bfr, acc[1][t], 0, 0, 0);
        }
    }

    // convert acc -> monotone u32 keys (EXACT, no bit-steal)
    float smc[8];
    #pragma unroll
    for (int t = 0; t < 8; ++t)
        smc[t] = sq[b * N_ + ((wv * 8 + t) << 4) + cl];

    unsigned karr[2][8][4];
    #pragma unroll
    for (int tl = 0; tl < 2; ++tl)
        #pragma unroll
        for (int t = 0; t < 8; ++t)
            #pragma unroll
            for (int r = 0; r < 4; ++r) {
                float d2 = fmaf(-2.f, acc[tl][t][r], smc[t] + sqn[tl * 16 + quad * 4 + r]);
                unsigned bits = __float_as_uint(d2);
                karr[tl][t][r] = bits ^ ((unsigned)((int)bits >> 31) | 0x80000000u);
            }

    // stage all 4 row-phases into registers
    unsigned vA[16], vB[16], vC[16], vD[16];
    STAGE_READ(0, vA);
    STAGE_READ(1, vB);
    STAGE_READ(2, vC);
    STAGE_READ(3, vD);

    int rbase = ((wv >> 1) << 2) + (wv & 1);
    int rowP0 = (b * N_ + n0 + rbase) * K_;
    int rowP1 = (b * N_ + n0 + rbase + 2) * K_;
    int rowP2 = (b * N_ + n0 + 16 + rbase) * K_;
    int rowP3 = (b * N_ + n0 + 16 + rbase + 2) * K_;

    unsigned mA1, mA2, jA1, jA2, mB1, mB2, jB1, jB2;
    unsigned mC1, mC2, jC1, jC2, mD1, mD2, jD1, jD2;
    TOP2_INIT(vA, mA1, mA2, jA1, jA2);
    TOP2_INIT(vB, mB1, mB2, jB1, jB2);
    TOP2_INIT(vC, mC1, mC2, jC1, jC2);
    TOP2_INIT(vD, mD1, mD2, jD1, jD2);

    #pragma unroll 1
    for (int q = 0; q < K_; ++q) {
        unsigned gA = mA1, gB = mB1, gC = mC1, gD = mD1;
        #pragma unroll
        for (int off = 1; off < 64; off <<= 1) {   // 4 independent chains: ILP
            gA = umin_(gA, (unsigned)__shfl_xor((int)gA, off));
            gB = umin_(gB, (unsigned)__shfl_xor((int)gB, off));
            gC = umin_(gC, (unsigned)__shfl_xor((int)gC, off));
            gD = umin_(gD, (unsigned)__shfl_xor((int)gD, off));
        }
        ROW_ROUND(vA, mA1, mA2, jA1, jA2, gA, rowP0);
        ROW_ROUND(vB, mB1, mB2, jB1, jB2, gB, rowP1);
        ROW_ROUND(vC, mC1, mC2, jC1, jC2, gC, rowP2);
        ROW_ROUND(vD, mD1, mD2, jD1, jD2, gD, rowP3);
    }
}

// ------- MFMA edge-MLP + maxpool: block = 8 points (72 edges, padded to 80 rows)
__global__ __launch_bounds__(512, 6) void k_edge(const float* __restrict__ featsT,
        const int* __restrict__ idx, const unsigned short* __restrict__ wf1,
        const unsigned short* __restrict__ wf2, const float* __restrict__ b1,
        const float* __restrict__ b2, float* __restrict__ msg)
{
    __shared__ __align__(16) char smem[52224];
    unsigned short* diffs = (unsigned short*)smem;
    unsigned short* cenb  = (unsigned short*)(smem + 21760);
    unsigned short* h2b   = (unsigned short*)smem;
    unsigned short* h1    = (unsigned short*)(smem + 26112);
    unsigned short* ccb   = (unsigned short*)(smem + 47872);
    __shared__ int nb[72];

    int L = blockIdx.x;                 // 2048 = 8 xcd * 256 slots
    int xcd = L & 7, slot = L >> 3;
    int b = xcd * 2 + (slot >> 7);
    int tile = slot & 127;
    int n0 = tile * 8;
    int tid = threadIdx.x;

    if (tid < 72) nb[tid] = idx[(b * N_ + n0 + tid / 9) * K_ + tid % 9];
    __syncthreads();

    // ---- gather: 64 threads per point; halves split the 9 edges 5/4
    {
        int g = tid >> 6, j = tid & 63;
        int chunk = j & 31, ch = chunk << 2, half = j >> 5;
        const float4* fT4 = (const float4*)featsT;
        float4 cv = fT4[(b * N_ + n0 + g) * 32 + chunk];
        if (half == 0) {
            u16x4 cb; cb.x = f2bf(cv.x); cb.y = f2bf(cv.y);
            cb.z = f2bf(cv.z); cb.w = f2bf(cv.w);
            *(u16x4*)&cenb[g * 136 + ch] = cb;
        }
        int qb = half ? 5 : 0, qe = half ? 9 : 5;
        for (int q = qb; q < qe; ++q) {
            int e = g * 9 + q;
            float4 nv = fT4[(b * N_ + nb[e]) * 32 + chunk];
            u16x4 db;
            db.x = f2bf(nv.x - cv.x); db.y = f2bf(nv.y - cv.y);
            db.z = f2bf(nv.z - cv.z); db.w = f2bf(nv.w - cv.w);
            *(u16x4*)&diffs[e * 136 + ch] = db;
        }
    }
    __syncthreads();

    int wv = tid >> 6, lane = tid & 63;
    int quad = lane >> 4, cl = lane & 15;
    const short8* w1f = (const short8*)wf1;
    const short8* w2f = (const short8*)wf2;

    // ---- G1a: centers @ W1_top + b1 -> cc
    {
        float b1v = b1[16 * wv + cl];
        f32x4 a = (f32x4){b1v, b1v, b1v, b1v};
        #pragma unroll
        for (int kk = 0; kk < 4; ++kk) {
            short8 af = *(const short8*)&cenb[cl * 136 + kk * 32 + quad * 8];
            short8 bf = w1f[(kk * 8 + wv) * 64 + lane];
            a = __builtin_amdgcn_mfma_f32_16x16x32_bf16(af, bf, a, 0, 0, 0);
        }
        #pragma unroll
        for (int r = 0; r < 4; ++r)
            ccb[(quad * 4 + r) * 136 + 16 * wv + cl] = f2bf(a[r]);
    }

    // ---- G1b: diffs @ W1_bot, + cc[point], leaky -> h1 (weights hoisted)
    {
        short8 wb[4];
        #pragma unroll
        for (int kb = 0; kb < 4; ++kb)
            wb[kb] = w1f[((kb + 4) * 8 + wv) * 64 + lane];
        #pragma unroll
        for (int t = 0; t < 5; ++t) {
            f32x4 a = (f32x4){0.f, 0.f, 0.f, 0.f};
            #pragma unroll
            for (int kb = 0; kb < 4; ++kb) {
                short8 af = *(const short8*)&diffs[(16 * t + cl) * 136 + kb * 32 + quad * 8];
                a = __builtin_amdgcn_mfma_f32_16x16x32_bf16(af, wb[kb], a, 0, 0, 0);
            }
            #pragma unroll
            for (int r = 0; r < 4; ++r) {
                int row = 16 * t + quad * 4 + r;
                int pt = row / 9; if (pt > 7) pt = 7;
                float v = a[r] + bf2f(ccb[pt * 136 + 16 * wv + cl]);
                v = (v >= 0.f) ? v : NEG_SLOPE * v;
                h1[row * 136 + 16 * wv + cl] = f2bf(v);
            }
        }
    }
    __syncthreads();

    // ---- GEMM2: h1 @ W2 -> h2 (bf16, aliases dead diffs; weights hoisted)
    {
        short8 wb[4];
        #pragma unroll
        for (int kb = 0; kb < 4; ++kb)
            wb[kb] = w2f[(kb * 8 + wv) * 64 + lane];
        #pragma unroll
        for (int t = 0; t < 5; ++t) {
            f32x4 a = (f32x4){0.f, 0.f, 0.f, 0.f};
            #pragma unroll
            for (int kb = 0; kb < 4; ++kb) {
                short8 af = *(const short8*)&h1[(16 * t + cl) * 136 + kb * 32 + quad * 8];
                a = __builtin_amdgcn_mfma_f32_16x16x32_bf16(af, wb[kb], a, 0, 0, 0);
            }
            #pragma unroll
            for (int r = 0; r < 4; ++r)
                h2b[(16 * t + quad * 4 + r) * 136 + 16 * wv + cl] = f2bf(a[r]);
        }
    }
    __syncthreads();

    // ---- maxpool over 9 edges/point + bias, write msg (B,C,N)
    int p = tid & 7, nb8 = tid >> 3;      // nb8: 0..63
    #pragma unroll
    for (int it = 0; it < 2; ++it) {
        int n = nb8 + 64 * it;
        float m = bf2f(h2b[(p * 9) * 136 + n]);
        #pragma unroll
        for (int q = 1; q < 9; ++q)
            m = fmaxf(m, bf2f(h2b[(p * 9 + q) * 136 + n]));
        msg[(b * C_ + n) * N_ + n0 + p] = m + b2[n];
    }
}

// ------------- BN partial sums (R20): 256 blocks = 2 per channel x 8 batches,
// block-reduce then 2 atomicAdds into bnacc (zeroed by k_stage).
__global__ __launch_bounds__(256) void k_bnpart(const float* __restrict__ msg,
        float* __restrict__ bnacc)
{
    int c = blockIdx.x >> 1, bh = blockIdx.x & 1, tid = threadIdx.x;
    const float4* m4 = (const float4*)msg;
    float4 s4 = {0.f, 0.f, 0.f, 0.f}, ss4 = {0.f, 0.f, 0.f, 0.f};
    #pragma unroll
    for (int bi = 0; bi < 8; ++bi) {
        int b = bh * 8 + bi;
        float4 v = m4[(b * C_ + c) * 256 + tid];
        s4.x += v.x; s4.y += v.y; s4.z += v.z; s4.w += v.w;
        ss4.x += v.x * v.x; ss4.y += v.y * v.y;
        ss4.z += v.z * v.z; ss4.w += v.w * v.w;
    }
    float s = (s4.x + s4.y) + (s4.z + s4.w);
    float ss = (ss4.x + ss4.y) + (ss4.z + ss4.w);
    __shared__ float rs[256], rss[256];
    rs[tid] = s; rss[tid] = ss;
    __syncthreads();
    for (int off = 128; off > 0; off >>= 1) {
        if (tid < off) { rs[tid] += rs[tid + off]; rss[tid] += rss[tid + off]; }
        __syncthreads();
    }
    if (tid == 0) {
        atomicAdd(&bnacc[2 * c], rs[0]);
        atomicAdd(&bnacc[2 * c + 1], rss[0]);
    }
}

// ------------- BN apply + residual + final ReLU (R20: scale/shift inline;
// each block covers exactly one (b,c) row so c is block-uniform).
__global__ __launch_bounds__(256) void k_final(const float* __restrict__ msg,
        const float* __restrict__ x, const float* __restrict__ bnacc,
        const float* __restrict__ gamma, const float* __restrict__ beta,
        float* __restrict__ out)
{
    int c = blockIdx.x & 127;
    float s = bnacc[2 * c], ss = bnacc[2 * c + 1];
    float mean = s / (float)(B_ * N_);
    float var = ss / (float)(B_ * N_) - mean * mean;
    float inv = 1.0f / sqrtf(var + BN_EPS);
    float g = gamma[c];
    float sc = g * inv;
    float sh = beta[c] - g * inv * mean;

    int i = blockIdx.x * 256 + threadIdx.x;
    float4 m4 = reinterpret_cast<const float4*>(msg)[i];
    float4 x4 = reinterpret_cast<const float4*>(x)[i];
    float4 o;
    o.x = fmaxf(m4.x * sc + sh + x4.x, 0.f);
    o.y = fmaxf(m4.y * sc + sh + x4.y, 0.f);
    o.z = fmaxf(m4.z * sc + sh + x4.z, 0.f);
    o.w = fmaxf(m4.w * sc + sh + x4.w, 0.f);
    reinterpret_cast<float4*>(out)[i] = o;
}

extern "C" void kernel_launch(void* const* d_in, const int* in_sizes, int n_in,
                              void* d_out, int out_size, void* d_ws, size_t ws_size,
                              hipStream_t stream)
{
    const float* x     = (const float*)d_in[0];
    const float* W1    = (const float*)d_in[1];
    const float* b1    = (const float*)d_in[2];
    const float* W2    = (const float*)d_in[3];
    const float* b2    = (const float*)d_in[4];
    const float* gamma = (const float*)d_in[5];
    const float* beta  = (const float*)d_in[6];
    float* out = (float*)d_out;

    float* ws     = (float*)d_ws;
    float* featsT = ws;                     // 8 MB, live through k_edge
    float* msg    = ws + 2097152;           // 8 MB; Bf aliases (dead before k_edge)
    unsigned short* Bf = (unsigned short*)(ws + 2097152);
    float* sq     = ws + 4194304;           // 16384
    float* bnacc  = ws + 4210688;           // 256 floats (sum, ss per channel)
    int*   idx    = (int*)(ws + 4210944);   // 147456 ints
    unsigned short* wf1 = (unsigned short*)(ws + 4358400);  // 32768 bf16
    unsigned short* wf2 = (unsigned short*)(ws + 4374784);  // 16384 bf16

    k_stage <<< 536, 256, 0, stream>>>(x, W1, W2, featsT, Bf, sq, wf1, wf2, bnacc);
    k_knn   <<< 512, 512, 0, stream>>>(Bf, sq, idx);
    k_edge  <<<2048, 512, 0, stream>>>(featsT, idx, wf1, wf2, b1, b2, msg);
    k_bnpart<<< 256, 256, 0, stream>>>(msg, bnacc);
    k_final <<<2048, 256, 0, stream>>>(msg, x, bnacc, gamma, beta, out);
}